// Round 25
// baseline (69.158 us; speedup 1.0000x reference)
//
#include <hip/hip_runtime.h>
#include <math.h>

#define B_    8
#define T_    2000
#define H_    256
#define FOUT_ 257
#define ALEN_ 128

typedef __attribute__((ext_vector_type(8))) short bf16x8;
typedef __attribute__((ext_vector_type(4))) float f32x4;
typedef __attribute__((ext_vector_type(8))) unsigned short u16x8;

// ---------------------------------------------------------------------------
__device__ __forceinline__ unsigned short f2bf(float x) {   // RNE
    unsigned u = __builtin_bit_cast(unsigned, x);
    return (unsigned short)((u + 0x7FFFu + ((u >> 16) & 1u)) >> 16);
}
// truncation split: x = hi + lo exactly at f32
__device__ __forceinline__ void split1(float x, unsigned short& h, unsigned short& l) {
    unsigned u = __builtin_bit_cast(unsigned, x);
    h = (unsigned short)(u >> 16);
    float hf = __builtin_bit_cast(float, u & 0xFFFF0000u);
    l = (unsigned short)(__builtin_bit_cast(unsigned, x - hf) >> 16);
}
__device__ __forceinline__ void split8(float4 f0, float4 f1, bf16x8& h, bf16x8& l) {
    float f[8] = {f0.x, f0.y, f0.z, f0.w, f1.x, f1.y, f1.z, f1.w};
#pragma unroll
    for (int i = 0; i < 8; ++i) {
        unsigned short hh, ll;
        split1(f[i], hh, ll);
        h[i] = (short)hh; l[i] = (short)ll;
    }
}
__device__ __forceinline__ void rne8(float4 f0, float4 f1, bf16x8& h) {
    float f[8] = {f0.x, f0.y, f0.z, f0.w, f1.x, f1.y, f1.z, f1.w};
#pragma unroll
    for (int i = 0; i < 8; ++i) h[i] = (short)f2bf(f[i]);
}
__device__ __forceinline__ void gld16(const void* g, void* l) {
    __builtin_amdgcn_global_load_lds(
        (const __attribute__((address_space(1))) unsigned*)g,
        (__attribute__((address_space(3))) unsigned*)l, 16, 0, 0);
}

// FA (frag-ordered) layout, keyed (row, k), KF = K/32 frags per 16-row tile:
//   rt=row>>4, rr=row&15, kf=k>>5, q=(k>>3)&3, e=k&7
//   elem offset = (((rt*KF + kf)*4 + q)*16 + rr)*8 + e

// ---------------------------------------------------------------------------
// prep v3 (R23/24-proven, unchanged).
__global__ __launch_bounds__(256) void prep(
    const float* __restrict__ k,
    const float* __restrict__ Ws, const float* __restrict__ We,
    const float* __restrict__ Wm,
    unsigned short* __restrict__ kfh, unsigned short* __restrict__ kfl,
    unsigned short* __restrict__ ktn,
    unsigned short* __restrict__ wsnh, unsigned short* __restrict__ wsnl,
    unsigned short* __restrict__ wenh,
    unsigned short* __restrict__ wmnh)
{
    __shared__ float tile[16][260];
    const int bx = blockIdx.x, tid = threadIdx.x;

    if (bx < 1008) {                     // ---- k prep: kFA + ktn
        const int bid = bx;
        const int b = bid / 126;
        const int g = bid % 126;
        const int s0 = g * 16;
        const int r = tid >> 4, cs = (tid & 15) * 16;
        const int s = s0 + r;
        if (s < T_) {
            const float* src = k + ((size_t)b * T_ + s) * H_ + cs;
#pragma unroll
            for (int i = 0; i < 2; ++i) {
                const float4 v0 = *(const float4*)(src + i * 8);
                const float4 v1 = *(const float4*)(src + i * 8 + 4);
                bf16x8 h, l;
                split8(v0, v1, h, l);
                const int kcol = cs + i * 8;
                const size_t off = ((((size_t)(b * 125 + g) * 8 + (kcol >> 5)) * 4 +
                                     ((kcol >> 3) & 3)) * 16 + r) * 8;
                *(bf16x8*)(kfh + off) = h;
                *(bf16x8*)(kfl + off) = l;
                const float ff[8] = {v0.x, v0.y, v0.z, v0.w, v1.x, v1.y, v1.z, v1.w};
#pragma unroll
                for (int j = 0; j < 8; ++j) tile[r][cs + i * 8 + j] = ff[j];
            }
        } else {
#pragma unroll
            for (int i = 0; i < 16; ++i) tile[r][cs + i] = 0.f;
        }
        __syncthreads();
        const int h = tid;
        const int ht = h >> 4, lq = h & 15;
        u16x8 o0, o1;
#pragma unroll
        for (int ss = 0; ss < 8; ++ss)
            o0[ss] = (unsigned short)(__builtin_bit_cast(unsigned, tile[ss][h]) >> 16);
#pragma unroll
        for (int ss = 0; ss < 8; ++ss)
            o1[ss] = (unsigned short)(__builtin_bit_cast(unsigned, tile[ss + 8][h]) >> 16);
        unsigned short* dst = ktn + (((size_t)(b * 16 + ht) * 126) + g) * 256 + lq * 8;
        *(u16x8*)(dst) = o0;
        *(u16x8*)(dst + 128) = o1;
    } else if (bx < 1264) {              // ---- W_score -> wsn (FA KF=8, hi+lo)
        const int g = bx - 1008;
        const int kk = tid;
        unsigned short h, l; split1(Ws[g * 256 + kk], h, l);
        const size_t off = ((((size_t)(g >> 4) * 8 + (kk >> 5)) * 4 +
                             ((kk >> 3) & 3)) * 16 + (g & 15)) * 8 + (kk & 7);
        wsnh[off] = h; wsnl[off] = l;
    } else if (bx < 1776) {              // ---- W_enh -> wenh (FA KF=16, hi only)
        const int idx = (bx - 1264) * 256 + tid;
        const int col = idx >> 9;
        const int kk = idx & 511;
        unsigned short h, l; split1(We[idx], h, l);
        const size_t off = ((((size_t)(col >> 4) * 16 + (kk >> 5)) * 4 +
                             ((kk >> 3) & 3)) * 16 + (col & 15)) * 8 + (kk & 7);
        wenh[off] = h;
    } else {                             // ---- W_mask -> wmnh (FA KF=8, hi only)
        const int col = bx - 1776;
        if (col < 320) {
            const int kk = tid;
            const float x = (col < FOUT_) ? Wm[col * 256 + kk] : 0.f;
            unsigned short h, l; split1(x, h, l);
            const size_t off = ((((size_t)(col >> 4) * 8 + (kk >> 5)) * 4 +
                                 ((kk >> 3) & 3)) * 16 + (col & 15)) * 8 + (kk & 7);
            wmnh[off] = h;
        }
    }
}

// ---------------------------------------------------------------------------
// Fused banded attention v10: QBLK=64 (grid 256 = 1 block/CU, single round),
// 1024 thr / 16 waves: sub = w&3 (16-row sub-tile), wp = w>>2 (quarter).
// Band window 192 (12 s-tiles, 6 PV sc). Per-row arithmetic identical to v9;
// wsn re-read amortized over 2x rows; out-of-range reads finite & masked.
// LDS hand-packed: QS @0 (64K) -> S @64K (50K); PH/PL alias dead QS after
// QK^T barrier. Peak 114KB.
__global__ __launch_bounds__(1024, 1) void band_attn_mfma(
    const float* __restrict__ qf,
    const unsigned short* __restrict__ wsnh, const unsigned short* __restrict__ wsnl,
    const unsigned short* __restrict__ kfh, const unsigned short* __restrict__ kfl,
    const unsigned short* __restrict__ ktn,
    unsigned short* __restrict__ Ch)
{
    __shared__ char LDSB[114 * 1024];
    // QSH @0 (32K: 64 rows x 512B, swizzled), QSL @32768
    // S @65536: 64 rows x 196 f32 (784B row stride)
    // after QK^T: PH @0 (64 x 400B), PL @25600

    const int bid = blockIdx.x;
    const int b = bid & 7;
    const int t0 = (bid >> 3) * 64;
    const int tid = threadIdx.x;
    const int w = tid >> 6, l = tid & 63;
    const int sub = w & 3;
    const int wp = w >> 2;          // 0..3
    const int lq = l & 15;
    const int lk = l >> 4;
    const int s_lo = max(0, t0 - ALEN_);
    const int srow = sub * 16;

    // ---- phase 0: qs(64 rows) = q @ Ws^T (3-term), A split inline ----
    {
        const int qr = min(t0 + srow + lq, T_ - 1);
        const float* qp = qf + ((size_t)b * T_ + qr) * H_ + lk * 8;
        bf16x8 aH[8], aL[8];
#pragma unroll
        for (int kg = 0; kg < 8; ++kg) {
            const float4 f0 = *(const float4*)(qp + kg * 32);
            const float4 f1 = *(const float4*)(qp + kg * 32 + 4);
            split8(f0, f1, aH[kg], aL[kg]);
        }
        for (int ht = wp; ht < 16; ht += 4) {
            f32x4 acc = {};
#pragma unroll
            for (int kg = 0; kg < 8; ++kg) {
                const size_t fo = ((size_t)(ht * 8 + kg)) * 1024 + (size_t)l * 16;
                const bf16x8 bh = *(const bf16x8*)((const char*)wsnh + fo);
                const bf16x8 bl = *(const bf16x8*)((const char*)wsnl + fo);
                acc = __builtin_amdgcn_mfma_f32_16x16x32_bf16(aH[kg], bh, acc, 0, 0, 0);
                acc = __builtin_amdgcn_mfma_f32_16x16x32_bf16(aH[kg], bl, acc, 0, 0, 0);
                acc = __builtin_amdgcn_mfma_f32_16x16x32_bf16(aL[kg], bh, acc, 0, 0, 0);
            }
#pragma unroll
            for (int r = 0; r < 4; ++r) {
                unsigned short h2, l2;
                split1(acc[r], h2, l2);
                const int t = srow + lk * 4 + r;                 // 0..63
                unsigned off = (unsigned)(t * 512 + (ht * 16 + lq) * 2);
                off ^= (unsigned)((t & 7) << 4);
                *(unsigned short*)(LDSB + off) = h2;             // QSH
                *(unsigned short*)(LDSB + 32768 + off) = l2;     // QSL
            }
        }
    }
    __syncthreads();

    // ---- QK^T: A from LDS qs (own sub), B from kFA; S @64K ----
    {
        bf16x8 aH[8], aL[8];
#pragma unroll
        for (int hc = 0; hc < 8; ++hc) {
            const int t = srow + lq;
            unsigned off = (unsigned)(t * 512 + hc * 64 + lk * 16);
            off ^= (unsigned)((t & 7) << 4);
            aH[hc] = *(const bf16x8*)(LDSB + off);
            aL[hc] = *(const bf16x8*)(LDSB + 32768 + off);
        }
        const int slo16 = s_lo >> 4;
        for (int st = wp; st < 12; st += 4) {
            f32x4 acc = {};
            const int rtk = b * 125 + slo16 + st;
#pragma unroll
            for (int hc = 0; hc < 8; ++hc) {
                const size_t ob = ((size_t)(rtk * 8 + hc)) * 1024 + (size_t)l * 16;
                const bf16x8 bh = *(const bf16x8*)((const char*)kfh + ob);
                const bf16x8 bl = *(const bf16x8*)((const char*)kfl + ob);
                acc = __builtin_amdgcn_mfma_f32_16x16x32_bf16(aH[hc], bh, acc, 0, 0, 0);
                acc = __builtin_amdgcn_mfma_f32_16x16x32_bf16(aH[hc], bl, acc, 0, 0, 0);
                acc = __builtin_amdgcn_mfma_f32_16x16x32_bf16(aL[hc], bh, acc, 0, 0, 0);
            }
#pragma unroll
            for (int r = 0; r < 4; ++r) {
                const int row = srow + lk * 4 + r;
                *(float*)(LDSB + 65536 + ((size_t)row * 196 + st * 16 + lq) * 4) = acc[r];
            }
        }
    }
    __syncthreads();

    // ---- softmax (band-masked, pre-scaled); 64 rows x 16 lanes ----
    {
        const int qq = tid >> 4, li = tid & 15;      // qq 0..63
        const int t = t0 + qq;
        const int jlo = max(0, t - ALEN_) - s_lo;
        const int jhi = t - s_lo;                    // <= 191
        const char* Srow = LDSB + 65536 + (size_t)qq * 784;
        float m = -INFINITY;
#pragma unroll
        for (int j = 0; j < 12; ++j) {
            const int s = li + j * 16;
            if (s >= jlo && s <= jhi) m = fmaxf(m, *(const float*)(Srow + s * 4));
        }
#pragma unroll
        for (int off = 8; off; off >>= 1) m = fmaxf(m, __shfl_xor(m, off));
        float sum = 0.f;
        float ev[12];
#pragma unroll
        for (int j = 0; j < 12; ++j) {
            const int s = li + j * 16;
            const float e = (s >= jlo && s <= jhi)
                ? expf(*(const float*)(Srow + s * 4) - m) : 0.f;
            ev[j] = e;
            sum += e;
        }
#pragma unroll
        for (int off = 8; off; off >>= 1) sum += __shfl_xor(sum, off);
        const float inv = 1.f / (sum + 1e-30f);
#pragma unroll
        for (int j = 0; j < 12; ++j) {
            const int s = li + j * 16;
            unsigned short hh2, ll2;
            split1(ev[j] * inv, hh2, ll2);
            *(unsigned short*)(LDSB + (size_t)qq * 400 + s * 2) = hh2;           // PH
            *(unsigned short*)(LDSB + 25600 + (size_t)qq * 400 + s * 2) = ll2;   // PL
        }
    }
    __syncthreads();

    // ---- PV (frag-ordered ktn); write c as RNE bf16-hi in FA (KF=8) ----
    const int gbase = s_lo >> 4;
    for (int ht = wp; ht < 16; ht += 4) {
        f32x4 acc = {};
        const unsigned short* ktb = ktn + ((size_t)(b * 16 + ht) * 126) * 256;
        const char* PHrow = LDSB + (size_t)(srow + lq) * 400;
        const char* PLrow = LDSB + 25600 + (size_t)(srow + lq) * 400;
#pragma unroll
        for (int sc = 0; sc < 6; ++sc) {
            const bf16x8 ph = *(const bf16x8*)(PHrow + sc * 64 + lk * 16);
            const bf16x8 pl = *(const bf16x8*)(PLrow + sc * 64 + lk * 16);
            const bf16x8 bt = *(const bf16x8*)(
                ktb + (size_t)(gbase + 2 * sc + (lk >> 1)) * 256 + (lk & 1) * 128 + lq * 8);
            acc = __builtin_amdgcn_mfma_f32_16x16x32_bf16(ph, bt, acc, 0, 0, 0);
            acc = __builtin_amdgcn_mfma_f32_16x16x32_bf16(pl, bt, acc, 0, 0, 0);
        }
        const int rt_c = b * 125 + ((t0 + srow) >> 4);
        const size_t base = (((size_t)rt_c * 8 + (ht >> 1)) * 4 +
                             ((ht & 1) * 2 + (lq >> 3))) * 16;
#pragma unroll
        for (int r = 0; r < 4; ++r) {
            const int trow = t0 + srow + lk * 4 + r;
            if (trow < T_) {
                const size_t o = (base + (lk * 4 + r)) * 8 + (lq & 7);
                Ch[o] = f2bf(acc[r]);
            }
        }
    }
}

// ---------------------------------------------------------------------------
// gemm_fused v7 (R24-proven, unchanged): pure-bf16 MLP, grid 250 x 64-row
// blocks, 512 thr; A panel 64KB LDS once; barrier-free K-loops; B hi-only
// read once per block.
__global__ __launch_bounds__(512) void gemm_fused(
    const unsigned short* __restrict__ ch,
    const float* __restrict__ qf,
    const unsigned short* __restrict__ wenh,
    const float* __restrict__ b_enh,
    const unsigned short* __restrict__ wmnh,
    const float* __restrict__ b_mask, float* __restrict__ out)
{
    __shared__ char LDSB[64 * 1024];
    // cAh @0 (32K), qAh @32K (32K); after phase1: EH @0 (32K, swizzled)

    const int bid = blockIdx.x;
    const int tid = threadIdx.x;
    const int w = tid >> 6, l = tid & 63;
    const int lq = l & 15, lk = l >> 4;

    // ---- stage c panel hi (FA-linear, direct to LDS) ----
#pragma unroll
    for (int p = 0; p < 4; ++p) {
        const size_t D = ((size_t)p * 512 + tid) * 16;     // 0..32767
        gld16((const char*)ch + (size_t)bid * 32768 + D, LDSB + D);
    }
    // ---- stage q panel (f32 load, RNE hi only, ds_write; FA-linear) ----
#pragma unroll
    for (int p = 0; p < 4; ++p) {
        const int off8 = p * 512 + tid;                    // 0..2047
        const int rr = off8 & 15, qq = (off8 >> 4) & 3;
        const int kf = (off8 >> 6) & 7, rtl = off8 >> 9;
        const float* src = qf + ((size_t)(bid * 64 + rtl * 16 + rr)) * H_ + kf * 32 + qq * 8;
        const float4 f0 = *(const float4*)(src);
        const float4 f1 = *(const float4*)(src + 4);
        bf16x8 h;
        rne8(f0, f1, h);
        *(bf16x8*)(LDSB + 32768 + (size_t)off8 * 16) = h;
    }
    __syncthreads();

    // ---- phase 1: enh = tanh([c,q]@Weh^T + be); wave w: ct {2w, 2w+1} ----
    f32x4 acc[4][2] = {};
    const int ct0 = 2 * w, ct1 = 2 * w + 1;
#pragma unroll
    for (int ph = 0; ph < 2; ++ph) {
        const char* Ah = LDSB + ph * 32768;
#pragma unroll
        for (int kf = 0; kf < 8; ++kf) {
            const size_t bo0 = ((size_t)(ct0 * 16 + ph * 8 + kf)) * 1024 + (size_t)l * 16;
            const size_t bo1 = ((size_t)(ct1 * 16 + ph * 8 + kf)) * 1024 + (size_t)l * 16;
            const bf16x8 bh0 = *(const bf16x8*)((const char*)wenh + bo0);
            const bf16x8 bh1 = *(const bf16x8*)((const char*)wenh + bo1);
#pragma unroll
            for (int rt = 0; rt < 4; ++rt) {
                const size_t ao = ((size_t)(rt * 8 + kf)) * 1024 + (size_t)l * 16;
                const bf16x8 ah = *(const bf16x8*)(Ah + ao);
                acc[rt][0] = __builtin_amdgcn_mfma_f32_16x16x32_bf16(ah, bh0, acc[rt][0], 0, 0, 0);
                acc[rt][1] = __builtin_amdgcn_mfma_f32_16x16x32_bf16(ah, bh1, acc[rt][1], 0, 0, 0);
            }
        }
    }
    __syncthreads();   // all waves done reading cA/qA before EH overwrite

    // ---- enh -> LDS EH (RNE hi, swizzled; 64 rows x 256 cols) ----
    {
        char* EH = LDSB;
#pragma unroll
        for (int cc = 0; cc < 2; ++cc) {
            const int col = (2 * w + cc) * 16 + lq;
            const float bv = b_enh[col];
#pragma unroll
            for (int rt = 0; rt < 4; ++rt) {
#pragma unroll
                for (int r = 0; r < 4; ++r) {
                    const int row = rt * 16 + lk * 4 + r;
                    unsigned off = (unsigned)(row * 512 + col * 2);
                    off ^= (unsigned)((row & 7) << 4);
                    *(unsigned short*)(EH + off) = f2bf(tanhf(acc[rt][cc][r] + bv));
                }
            }
        }
    }
    __syncthreads();

    // ---- phase 2: out = sigmoid(enh @ Wmh^T + bm); wave w: ct = w + 8i ----
    {
        const char* EH = LDSB;
        f32x4 o2[4][3] = {};
#pragma unroll
        for (int kf = 0; kf < 8; ++kf) {
            bf16x8 bh[3];
#pragma unroll
            for (int i = 0; i < 3; ++i) {
                const int ct = w + 8 * i;
                if (ct < 20) {
                    const size_t bo = ((size_t)(ct * 8 + kf)) * 1024 + (size_t)l * 16;
                    bh[i] = *(const bf16x8*)((const char*)wmnh + bo);
                }
            }
#pragma unroll
            for (int rt = 0; rt < 4; ++rt) {
                const int trow = rt * 16 + lq;
                unsigned aoff = (unsigned)(trow * 512 + kf * 64 + lk * 16);
                aoff ^= (unsigned)((trow & 7) << 4);
                const bf16x8 ah = *(const bf16x8*)(EH + aoff);
#pragma unroll
                for (int i = 0; i < 3; ++i) {
                    const int ct = w + 8 * i;
                    if (ct < 20) {
                        o2[rt][i] = __builtin_amdgcn_mfma_f32_16x16x32_bf16(ah, bh[i], o2[rt][i], 0, 0, 0);
                    }
                }
            }
        }
#pragma unroll
        for (int i = 0; i < 3; ++i) {
            const int ct = w + 8 * i;
            if (ct < 20) {
                const int col = ct * 16 + lq;
                if (col < FOUT_) {
                    const float bv = b_mask[col];
#pragma unroll
                    for (int rt = 0; rt < 4; ++rt) {
#pragma unroll
                        for (int r = 0; r < 4; ++r) {
                            const int row = bid * 64 + rt * 16 + lk * 4 + r;
                            out[(size_t)row * FOUT_ + col] =
                                1.f / (1.f + expf(-(o2[rt][i][r] + bv)));
                        }
                    }
                }
            }
        }
    }
}

// ---------------------------------------------------------------------------
extern "C" void kernel_launch(void* const* d_in, const int* in_sizes, int n_in,
                              void* d_out, int out_size, void* d_ws, size_t ws_size,
                              hipStream_t stream)
{
    const float* k       = (const float*)d_in[0];
    const float* q       = (const float*)d_in[1];
    const float* W_score = (const float*)d_in[2];
    const float* W_enh   = (const float*)d_in[3];
    const float* b_enh   = (const float*)d_in[4];
    const float* W_mask  = (const float*)d_in[5];
    const float* b_mask  = (const float*)d_in[6];
    float* out = (float*)d_out;

    const size_t MH = (size_t)B_ * T_ * H_;          // 4.096M elems
    unsigned short* ch  = (unsigned short*)d_ws;
    unsigned short* kfh = ch + MH;
    unsigned short* kfl = kfh + MH;
    unsigned short* ktn = kfl + MH;                  // 8*16*126*256
    unsigned short* wsnh = ktn + (size_t)B_ * 16 * 126 * 256;
    unsigned short* wsnl = wsnh + 65536;
    unsigned short* wenh = wsnl + 65536;
    unsigned short* wmnh = wenh + 131072;            // 320x256 FA (hi only)

    dim3 blk(256);

    prep<<<dim3(2288), blk, 0, stream>>>(
        k, W_score, W_enh, W_mask,
        kfh, kfl, ktn, wsnh, wsnl, wenh, wmnh);

    band_attn_mfma<<<dim3(256), dim3(1024), 0, stream>>>(
        q, wsnh, wsnl, kfh, kfl, ktn, ch);

    gemm_fused<<<dim3(250), dim3(512), 0, stream>>>(
        ch, q, wenh, b_enh, wmnh, b_mask, out);
}

// Round 26
// 67.484 us; speedup vs baseline: 1.0248x; 1.0248x over previous
//
#include <hip/hip_runtime.h>
#include <math.h>

#define B_    8
#define T_    2000
#define H_    256
#define FOUT_ 257
#define ALEN_ 128

typedef __attribute__((ext_vector_type(8))) short bf16x8;
typedef __attribute__((ext_vector_type(4))) float f32x4;
typedef __attribute__((ext_vector_type(8))) unsigned short u16x8;

// ---------------------------------------------------------------------------
__device__ __forceinline__ unsigned short f2bf(float x) {   // RNE
    unsigned u = __builtin_bit_cast(unsigned, x);
    return (unsigned short)((u + 0x7FFFu + ((u >> 16) & 1u)) >> 16);
}
// truncation split: x = hi + lo exactly at f32
__device__ __forceinline__ void split1(float x, unsigned short& h, unsigned short& l) {
    unsigned u = __builtin_bit_cast(unsigned, x);
    h = (unsigned short)(u >> 16);
    float hf = __builtin_bit_cast(float, u & 0xFFFF0000u);
    l = (unsigned short)(__builtin_bit_cast(unsigned, x - hf) >> 16);
}
__device__ __forceinline__ void split8(float4 f0, float4 f1, bf16x8& h, bf16x8& l) {
    float f[8] = {f0.x, f0.y, f0.z, f0.w, f1.x, f1.y, f1.z, f1.w};
#pragma unroll
    for (int i = 0; i < 8; ++i) {
        unsigned short hh, ll;
        split1(f[i], hh, ll);
        h[i] = (short)hh; l[i] = (short)ll;
    }
}
__device__ __forceinline__ void rne8(float4 f0, float4 f1, bf16x8& h) {
    float f[8] = {f0.x, f0.y, f0.z, f0.w, f1.x, f1.y, f1.z, f1.w};
#pragma unroll
    for (int i = 0; i < 8; ++i) h[i] = (short)f2bf(f[i]);
}
__device__ __forceinline__ void gld16(const void* g, void* l) {
    __builtin_amdgcn_global_load_lds(
        (const __attribute__((address_space(1))) unsigned*)g,
        (__attribute__((address_space(3))) unsigned*)l, 16, 0, 0);
}

// FA (frag-ordered) layout, keyed (row, k), KF = K/32 frags per 16-row tile:
//   rt=row>>4, rr=row&15, kf=k>>5, q=(k>>3)&3, e=k&7
//   elem offset = (((rt*KF + kf)*4 + q)*16 + rr)*8 + e

// ---------------------------------------------------------------------------
// prep v3 (R23/24-proven, unchanged).
__global__ __launch_bounds__(256) void prep(
    const float* __restrict__ k,
    const float* __restrict__ Ws, const float* __restrict__ We,
    const float* __restrict__ Wm,
    unsigned short* __restrict__ kfh, unsigned short* __restrict__ kfl,
    unsigned short* __restrict__ ktn,
    unsigned short* __restrict__ wsnh, unsigned short* __restrict__ wsnl,
    unsigned short* __restrict__ wenh,
    unsigned short* __restrict__ wmnh)
{
    __shared__ float tile[16][260];
    const int bx = blockIdx.x, tid = threadIdx.x;

    if (bx < 1008) {                     // ---- k prep: kFA + ktn
        const int bid = bx;
        const int b = bid / 126;
        const int g = bid % 126;
        const int s0 = g * 16;
        const int r = tid >> 4, cs = (tid & 15) * 16;
        const int s = s0 + r;
        if (s < T_) {
            const float* src = k + ((size_t)b * T_ + s) * H_ + cs;
#pragma unroll
            for (int i = 0; i < 2; ++i) {
                const float4 v0 = *(const float4*)(src + i * 8);
                const float4 v1 = *(const float4*)(src + i * 8 + 4);
                bf16x8 h, l;
                split8(v0, v1, h, l);
                const int kcol = cs + i * 8;
                const size_t off = ((((size_t)(b * 125 + g) * 8 + (kcol >> 5)) * 4 +
                                     ((kcol >> 3) & 3)) * 16 + r) * 8;
                *(bf16x8*)(kfh + off) = h;
                *(bf16x8*)(kfl + off) = l;
                const float ff[8] = {v0.x, v0.y, v0.z, v0.w, v1.x, v1.y, v1.z, v1.w};
#pragma unroll
                for (int j = 0; j < 8; ++j) tile[r][cs + i * 8 + j] = ff[j];
            }
        } else {
#pragma unroll
            for (int i = 0; i < 16; ++i) tile[r][cs + i] = 0.f;
        }
        __syncthreads();
        const int h = tid;
        const int ht = h >> 4, lq = h & 15;
        u16x8 o0, o1;
#pragma unroll
        for (int ss = 0; ss < 8; ++ss)
            o0[ss] = (unsigned short)(__builtin_bit_cast(unsigned, tile[ss][h]) >> 16);
#pragma unroll
        for (int ss = 0; ss < 8; ++ss)
            o1[ss] = (unsigned short)(__builtin_bit_cast(unsigned, tile[ss + 8][h]) >> 16);
        unsigned short* dst = ktn + (((size_t)(b * 16 + ht) * 126) + g) * 256 + lq * 8;
        *(u16x8*)(dst) = o0;
        *(u16x8*)(dst + 128) = o1;
    } else if (bx < 1264) {              // ---- W_score -> wsn (FA KF=8, hi+lo)
        const int g = bx - 1008;
        const int kk = tid;
        unsigned short h, l; split1(Ws[g * 256 + kk], h, l);
        const size_t off = ((((size_t)(g >> 4) * 8 + (kk >> 5)) * 4 +
                             ((kk >> 3) & 3)) * 16 + (g & 15)) * 8 + (kk & 7);
        wsnh[off] = h; wsnl[off] = l;
    } else if (bx < 1776) {              // ---- W_enh -> wenh (FA KF=16, hi only)
        const int idx = (bx - 1264) * 256 + tid;
        const int col = idx >> 9;
        const int kk = idx & 511;
        unsigned short h, l; split1(We[idx], h, l);
        const size_t off = ((((size_t)(col >> 4) * 16 + (kk >> 5)) * 4 +
                             ((kk >> 3) & 3)) * 16 + (col & 15)) * 8 + (kk & 7);
        wenh[off] = h;
    } else {                             // ---- W_mask -> wmnh (FA KF=8, hi only)
        const int col = bx - 1776;
        if (col < 320) {
            const int kk = tid;
            const float x = (col < FOUT_) ? Wm[col * 256 + kk] : 0.f;
            unsigned short h, l; split1(x, h, l);
            const size_t off = ((((size_t)(col >> 4) * 8 + (kk >> 5)) * 4 +
                                 ((kk >> 3) & 3)) * 16 + (col & 15)) * 8 + (kk & 7);
            wmnh[off] = h;
        }
    }
}

// ---------------------------------------------------------------------------
// Fused banded attention v9 (R24-proven, reverted from v10): QBLK=32,
// 512 thr / 8 waves, grid 504, b=bid&7 XCD-local; PV writes RNE bf16-hi c.
__global__ __launch_bounds__(512) void band_attn_mfma(
    const float* __restrict__ qf,
    const unsigned short* __restrict__ wsnh, const unsigned short* __restrict__ wsnl,
    const unsigned short* __restrict__ kfh, const unsigned short* __restrict__ kfl,
    const unsigned short* __restrict__ ktn,
    unsigned short* __restrict__ Ch)
{
    __shared__ float S[32][164];
    __shared__ unsigned short PH[32][168];
    __shared__ unsigned short PL[32][168];
    __shared__ unsigned short QSH[32 * 256];
    __shared__ unsigned short QSL[32 * 256];

    const int bid = blockIdx.x;
    const int b = bid & 7;
    const int t0 = (bid >> 3) * 32;
    const int tid = threadIdx.x;
    const int w = tid >> 6, l = tid & 63;
    const int sub = w & 1;
    const int wp = w >> 1;
    const int lq = l & 15;
    const int lk = l >> 4;
    const int s_lo = max(0, t0 - ALEN_);
    const int srow = sub * 16;

    // ---- phase 0: qs(32 rows) = q @ Ws^T (3-term), A split inline ----
    {
        const int qr = min(t0 + srow + lq, T_ - 1);
        const float* qp = qf + ((size_t)b * T_ + qr) * H_ + lk * 8;
        bf16x8 aH[8], aL[8];
#pragma unroll
        for (int kg = 0; kg < 8; ++kg) {
            const float4 f0 = *(const float4*)(qp + kg * 32);
            const float4 f1 = *(const float4*)(qp + kg * 32 + 4);
            split8(f0, f1, aH[kg], aL[kg]);
        }
        for (int ht = wp; ht < 16; ht += 4) {
            f32x4 acc = {};
#pragma unroll
            for (int kg = 0; kg < 8; ++kg) {
                const size_t fo = ((size_t)(ht * 8 + kg)) * 1024 + (size_t)l * 16;
                const bf16x8 bh = *(const bf16x8*)((const char*)wsnh + fo);
                const bf16x8 bl = *(const bf16x8*)((const char*)wsnl + fo);
                acc = __builtin_amdgcn_mfma_f32_16x16x32_bf16(aH[kg], bh, acc, 0, 0, 0);
                acc = __builtin_amdgcn_mfma_f32_16x16x32_bf16(aH[kg], bl, acc, 0, 0, 0);
                acc = __builtin_amdgcn_mfma_f32_16x16x32_bf16(aL[kg], bh, acc, 0, 0, 0);
            }
#pragma unroll
            for (int r = 0; r < 4; ++r) {
                unsigned short h2, l2;
                split1(acc[r], h2, l2);
                const int t = srow + lk * 4 + r;
                unsigned off = (unsigned)(t * 512 + (ht * 16 + lq) * 2);
                off ^= (unsigned)((t & 7) << 4);
                *(unsigned short*)((char*)QSH + off) = h2;
                *(unsigned short*)((char*)QSL + off) = l2;
            }
        }
    }
    __syncthreads();

    // ---- QK^T: A from LDS qs (own sub), B from kFA ----
    {
        bf16x8 aH[8], aL[8];
#pragma unroll
        for (int hc = 0; hc < 8; ++hc) {
            const int t = srow + lq;
            unsigned off = (unsigned)(t * 512 + hc * 64 + lk * 16);
            off ^= (unsigned)((t & 7) << 4);
            aH[hc] = *(const bf16x8*)((const char*)QSH + off);
            aL[hc] = *(const bf16x8*)((const char*)QSL + off);
        }
        const int slo16 = s_lo >> 4;
        for (int st = wp; st < 10; st += 4) {
            f32x4 acc = {};
            const int rtk = b * 125 + slo16 + st;
#pragma unroll
            for (int hc = 0; hc < 8; ++hc) {
                const size_t ob = ((size_t)(rtk * 8 + hc)) * 1024 + (size_t)l * 16;
                const bf16x8 bh = *(const bf16x8*)((const char*)kfh + ob);
                const bf16x8 bl = *(const bf16x8*)((const char*)kfl + ob);
                acc = __builtin_amdgcn_mfma_f32_16x16x32_bf16(aH[hc], bh, acc, 0, 0, 0);
                acc = __builtin_amdgcn_mfma_f32_16x16x32_bf16(aH[hc], bl, acc, 0, 0, 0);
                acc = __builtin_amdgcn_mfma_f32_16x16x32_bf16(aL[hc], bh, acc, 0, 0, 0);
            }
#pragma unroll
            for (int r = 0; r < 4; ++r)
                S[srow + lk * 4 + r][st * 16 + lq] = acc[r];
        }
    }
    __syncthreads();

    // ---- softmax (band-masked, P pre-scaled by 1/denom); 16 lanes/row ----
    {
        const int qq = tid >> 4, li = tid & 15;
        const int t = t0 + qq;
        const int jlo = max(0, t - ALEN_) - s_lo;
        const int jhi = t - s_lo;
        float m = -INFINITY;
#pragma unroll
        for (int j = 0; j < 10; ++j) {
            const int s = li + j * 16;
            if (s >= jlo && s <= jhi) m = fmaxf(m, S[qq][s]);
        }
#pragma unroll
        for (int off = 8; off; off >>= 1) m = fmaxf(m, __shfl_xor(m, off));
        float sum = 0.f;
#pragma unroll
        for (int j = 0; j < 10; ++j) {
            const int s = li + j * 16;
            const float e = (s >= jlo && s <= jhi) ? expf(S[qq][s] - m) : 0.f;
            S[qq][s] = e;
            sum += e;
        }
#pragma unroll
        for (int off = 8; off; off >>= 1) sum += __shfl_xor(sum, off);
        const float inv = 1.f / (sum + 1e-30f);
#pragma unroll
        for (int j = 0; j < 10; ++j) {
            const int s = li + j * 16;
            unsigned short hh2, ll2;
            split1(S[qq][s] * inv, hh2, ll2);
            PH[qq][s] = hh2;
            PL[qq][s] = ll2;
        }
    }
    __syncthreads();

    // ---- PV (frag-ordered ktn); write c as RNE bf16-hi in FA (KF=8) ----
    const int gbase = s_lo >> 4;
    for (int ht = wp; ht < 16; ht += 4) {
        f32x4 acc = {};
        const unsigned short* ktb = ktn + ((size_t)(b * 16 + ht) * 126) * 256;
#pragma unroll
        for (int sc = 0; sc < 5; ++sc) {
            const bf16x8 ph = *(const bf16x8*)((const char*)&PH[srow + lq][0] + sc * 64 + lk * 16);
            const bf16x8 pl = *(const bf16x8*)((const char*)&PL[srow + lq][0] + sc * 64 + lk * 16);
            const bf16x8 bt = *(const bf16x8*)(
                ktb + (size_t)(gbase + 2 * sc + (lk >> 1)) * 256 + (lk & 1) * 128 + lq * 8);
            acc = __builtin_amdgcn_mfma_f32_16x16x32_bf16(ph, bt, acc, 0, 0, 0);
            acc = __builtin_amdgcn_mfma_f32_16x16x32_bf16(pl, bt, acc, 0, 0, 0);
        }
        const int rt_c = b * 125 + ((t0 + srow) >> 4);
        const size_t base = (((size_t)rt_c * 8 + (ht >> 1)) * 4 +
                             ((ht & 1) * 2 + (lq >> 3))) * 16;
#pragma unroll
        for (int r = 0; r < 4; ++r) {
            const int trow = t0 + srow + lk * 4 + r;
            if (trow < T_) {
                const size_t o = (base + (lk * 4 + r)) * 8 + (lq & 7);
                Ch[o] = f2bf(acc[r]);
            }
        }
    }
}

// ---------------------------------------------------------------------------
// gemm_fused v7 (R24-proven, unchanged): pure-bf16 MLP, grid 250 x 64-row
// blocks, 512 thr; A panel 64KB LDS once; barrier-free K-loops; B hi-only
// read once per block.
__global__ __launch_bounds__(512) void gemm_fused(
    const unsigned short* __restrict__ ch,
    const float* __restrict__ qf,
    const unsigned short* __restrict__ wenh,
    const float* __restrict__ b_enh,
    const unsigned short* __restrict__ wmnh,
    const float* __restrict__ b_mask, float* __restrict__ out)
{
    __shared__ char LDSB[64 * 1024];
    // cAh @0 (32K), qAh @32K (32K); after phase1: EH @0 (32K, swizzled)

    const int bid = blockIdx.x;
    const int tid = threadIdx.x;
    const int w = tid >> 6, l = tid & 63;
    const int lq = l & 15, lk = l >> 4;

    // ---- stage c panel hi (FA-linear, direct to LDS) ----
#pragma unroll
    for (int p = 0; p < 4; ++p) {
        const size_t D = ((size_t)p * 512 + tid) * 16;     // 0..32767
        gld16((const char*)ch + (size_t)bid * 32768 + D, LDSB + D);
    }
    // ---- stage q panel (f32 load, RNE hi only, ds_write; FA-linear) ----
#pragma unroll
    for (int p = 0; p < 4; ++p) {
        const int off8 = p * 512 + tid;                    // 0..2047
        const int rr = off8 & 15, qq = (off8 >> 4) & 3;
        const int kf = (off8 >> 6) & 7, rtl = off8 >> 9;
        const float* src = qf + ((size_t)(bid * 64 + rtl * 16 + rr)) * H_ + kf * 32 + qq * 8;
        const float4 f0 = *(const float4*)(src);
        const float4 f1 = *(const float4*)(src + 4);
        bf16x8 h;
        rne8(f0, f1, h);
        *(bf16x8*)(LDSB + 32768 + (size_t)off8 * 16) = h;
    }
    __syncthreads();

    // ---- phase 1: enh = tanh([c,q]@Weh^T + be); wave w: ct {2w, 2w+1} ----
    f32x4 acc[4][2] = {};
    const int ct0 = 2 * w, ct1 = 2 * w + 1;
#pragma unroll
    for (int ph = 0; ph < 2; ++ph) {
        const char* Ah = LDSB + ph * 32768;
#pragma unroll
        for (int kf = 0; kf < 8; ++kf) {
            const size_t bo0 = ((size_t)(ct0 * 16 + ph * 8 + kf)) * 1024 + (size_t)l * 16;
            const size_t bo1 = ((size_t)(ct1 * 16 + ph * 8 + kf)) * 1024 + (size_t)l * 16;
            const bf16x8 bh0 = *(const bf16x8*)((const char*)wenh + bo0);
            const bf16x8 bh1 = *(const bf16x8*)((const char*)wenh + bo1);
#pragma unroll
            for (int rt = 0; rt < 4; ++rt) {
                const size_t ao = ((size_t)(rt * 8 + kf)) * 1024 + (size_t)l * 16;
                const bf16x8 ah = *(const bf16x8*)(Ah + ao);
                acc[rt][0] = __builtin_amdgcn_mfma_f32_16x16x32_bf16(ah, bh0, acc[rt][0], 0, 0, 0);
                acc[rt][1] = __builtin_amdgcn_mfma_f32_16x16x32_bf16(ah, bh1, acc[rt][1], 0, 0, 0);
            }
        }
    }
    __syncthreads();   // all waves done reading cA/qA before EH overwrite

    // ---- enh -> LDS EH (RNE hi, swizzled; 64 rows x 256 cols) ----
    {
        char* EH = LDSB;
#pragma unroll
        for (int cc = 0; cc < 2; ++cc) {
            const int col = (2 * w + cc) * 16 + lq;
            const float bv = b_enh[col];
#pragma unroll
            for (int rt = 0; rt < 4; ++rt) {
#pragma unroll
                for (int r = 0; r < 4; ++r) {
                    const int row = rt * 16 + lk * 4 + r;
                    unsigned off = (unsigned)(row * 512 + col * 2);
                    off ^= (unsigned)((row & 7) << 4);
                    *(unsigned short*)(EH + off) = f2bf(tanhf(acc[rt][cc][r] + bv));
                }
            }
        }
    }
    __syncthreads();

    // ---- phase 2: out = sigmoid(enh @ Wmh^T + bm); wave w: ct = w + 8i ----
    {
        const char* EH = LDSB;
        f32x4 o2[4][3] = {};
#pragma unroll
        for (int kf = 0; kf < 8; ++kf) {
            bf16x8 bh[3];
#pragma unroll
            for (int i = 0; i < 3; ++i) {
                const int ct = w + 8 * i;
                if (ct < 20) {
                    const size_t bo = ((size_t)(ct * 8 + kf)) * 1024 + (size_t)l * 16;
                    bh[i] = *(const bf16x8*)((const char*)wmnh + bo);
                }
            }
#pragma unroll
            for (int rt = 0; rt < 4; ++rt) {
                const int trow = rt * 16 + lq;
                unsigned aoff = (unsigned)(trow * 512 + kf * 64 + lk * 16);
                aoff ^= (unsigned)((trow & 7) << 4);
                const bf16x8 ah = *(const bf16x8*)(EH + aoff);
#pragma unroll
                for (int i = 0; i < 3; ++i) {
                    const int ct = w + 8 * i;
                    if (ct < 20) {
                        o2[rt][i] = __builtin_amdgcn_mfma_f32_16x16x32_bf16(ah, bh[i], o2[rt][i], 0, 0, 0);
                    }
                }
            }
        }
#pragma unroll
        for (int i = 0; i < 3; ++i) {
            const int ct = w + 8 * i;
            if (ct < 20) {
                const int col = ct * 16 + lq;
                if (col < FOUT_) {
                    const float bv = b_mask[col];
#pragma unroll
                    for (int rt = 0; rt < 4; ++rt) {
#pragma unroll
                        for (int r = 0; r < 4; ++r) {
                            const int row = bid * 64 + rt * 16 + lk * 4 + r;
                            out[(size_t)row * FOUT_ + col] =
                                1.f / (1.f + expf(-(o2[rt][i][r] + bv)));
                        }
                    }
                }
            }
        }
    }
}

// ---------------------------------------------------------------------------
extern "C" void kernel_launch(void* const* d_in, const int* in_sizes, int n_in,
                              void* d_out, int out_size, void* d_ws, size_t ws_size,
                              hipStream_t stream)
{
    const float* k       = (const float*)d_in[0];
    const float* q       = (const float*)d_in[1];
    const float* W_score = (const float*)d_in[2];
    const float* W_enh   = (const float*)d_in[3];
    const float* b_enh   = (const float*)d_in[4];
    const float* W_mask  = (const float*)d_in[5];
    const float* b_mask  = (const float*)d_in[6];
    float* out = (float*)d_out;

    const size_t MH = (size_t)B_ * T_ * H_;          // 4.096M elems
    unsigned short* ch  = (unsigned short*)d_ws;
    unsigned short* kfh = ch + MH;
    unsigned short* kfl = kfh + MH;
    unsigned short* ktn = kfl + MH;                  // 8*16*126*256
    unsigned short* wsnh = ktn + (size_t)B_ * 16 * 126 * 256;
    unsigned short* wsnl = wsnh + 65536;
    unsigned short* wenh = wsnl + 65536;
    unsigned short* wmnh = wenh + 131072;            // 320x256 FA (hi only)

    dim3 blk(256);

    prep<<<dim3(2288), blk, 0, stream>>>(
        k, W_score, W_enh, W_mask,
        kfh, kfl, ktn, wsnh, wsnl, wenh, wmnh);

    band_attn_mfma<<<dim3(504), dim3(512), 0, stream>>>(
        q, wsnh, wsnl, kfh, kfl, ktn, ch);

    gemm_fused<<<dim3(250), dim3(512), 0, stream>>>(
        ch, q, wenh, b_enh, wmnh, b_mask, out);
}